// Round 2
// baseline (130.336 us; speedup 1.0000x reference)
//
#include <hip/hip_runtime.h>

#define D 128
#define LAT 3
#define SD 22

// ---------------------------------------------------------------------------
// Kernel 1: fold the two linear chains into fused affine maps, stored in ws:
//   ws[0..383]    : J_enc [3][128]  = We3@We2@We1
//   ws[384..386]  : b_enc [3]       = We3@(We2@be1 + be2) + be3
//   ws[512..1023] : J_dec4 [128][4] = (J_dec[o][0..2], b_dec[o])
//                   J_dec = Wd3@Wd2@Wd1, b_dec = Wd3@(Wd2@bd1 + bd2) + bd3
// One block, 256 threads. Rewrites every used slot each call (deterministic).
// ---------------------------------------------------------------------------
__global__ __launch_bounds__(256) void fuse_weights(
    const float* __restrict__ We1, const float* __restrict__ be1,
    const float* __restrict__ We2, const float* __restrict__ be2,
    const float* __restrict__ We3, const float* __restrict__ be3,
    const float* __restrict__ Wd1, const float* __restrict__ bd1,
    const float* __restrict__ Wd2, const float* __restrict__ bd2,
    const float* __restrict__ Wd3, const float* __restrict__ bd3,
    float* __restrict__ ws)
{
    __shared__ float A1[3][64];   // We3@We2
    __shared__ float B1[64][3];   // Wd2@Wd1
    __shared__ float t2d[64];     // Wd2@bd1 + bd2
    const int t = threadIdx.x;

    if (t < 192) {
        {   // A1[r][c], r<3, c<64: dot over 32
            int r = t >> 6, c = t & 63;
            float s = 0.f;
            #pragma unroll 8
            for (int i = 0; i < 32; ++i) s += We3[r * 32 + i] * We2[i * 64 + c];
            A1[r][c] = s;
        }
        {   // B1[o][l], o<64, l<3: dot over 32
            int o = t / 3, l = t - o * 3;
            float s = 0.f;
            #pragma unroll 8
            for (int i = 0; i < 32; ++i) s += Wd2[o * 32 + i] * Wd1[i * 3 + l];
            B1[o][l] = s;
        }
    } else {
        int i = t - 192;  // 0..63
        float s = bd2[i];
        #pragma unroll 8
        for (int j = 0; j < 32; ++j) s += Wd2[i * 32 + j] * bd1[j];
        t2d[i] = s;
    }
    __syncthreads();

    // J_enc [3][128]: dot over 64
    for (int e = t; e < 3 * D; e += 256) {
        int r = e >> 7, c = e & 127;
        float s = 0.f;
        #pragma unroll 8
        for (int j = 0; j < 64; ++j) s += A1[r][j] * We1[j * D + c];
        ws[e] = s;
    }
    // b_enc [3]
    if (t < 3) {
        float s = be3[t];
        #pragma unroll 8
        for (int j = 0; j < 64; ++j) s += A1[t][j] * be1[j];
        #pragma unroll 8
        for (int i = 0; i < 32; ++i) s += We3[t * 32 + i] * be2[i];
        ws[384 + t] = s;
    }
    // J_dec4 [128][4]
    if (t < 128) {
        float s0 = 0.f, s1 = 0.f, s2 = 0.f, sb = bd3[t];
        #pragma unroll 8
        for (int j = 0; j < 64; ++j) {
            float w = Wd3[t * 64 + j];
            s0 += w * B1[j][0];
            s1 += w * B1[j][1];
            s2 += w * B1[j][2];
            sb += w * t2d[j];
        }
        ((float4*)(ws + 512))[t] = make_float4(s0, s1, s2, sb);
    }
}

// ---------------------------------------------------------------------------
// Kernel 2: one half-wave (32 lanes) per row, TWO rows per iteration
// (rows r and r+8 per half), with one-iteration software prefetch of the
// next 4 float4 loads. 12 reduction values share one interleaved 5-step
// shuffle butterfly (2x ILP on the chain); 8 loads in flight per wave.
// Output layout (flat, in return order):
//   z   @ 0      [N,3]
//   dz  @ 3N     [N,3]
//   dzb @ 6N     [N,3]
//   xb  @ 9N     [N,128]
//   dxb @ 137N   [N,128]
// ---------------------------------------------------------------------------

// per-row epilogue: SINDy library + dzb + all 5 output stores
#define EMIT_ROW(ROW, Z0, Z1, Z2, DV0, DV1, DV2)                              \
  {                                                                           \
    const float z0 = (Z0) + benc0, z1 = (Z1) + benc1, z2 = (Z2) + benc2;      \
    const float q00 = z0*z0, q01 = z0*z1, q02 = z0*z2;                        \
    const float q11 = z1*z1, q12 = z1*z2, q22 = z2*z2;                        \
    float th[SD];                                                             \
    th[0]=1.f; th[1]=1.f; th[2]=1.f;                                          \
    th[3]=z0;  th[4]=z1;  th[5]=z2;                                           \
    th[6]=q00; th[7]=q01; th[8]=q02; th[9]=q11; th[10]=q12; th[11]=q22;       \
    th[12]=q00*z0; th[13]=q00*z1; th[14]=q00*z2;                              \
    th[15]=q11*z0; th[16]=q12*z0; th[17]=q22*z0;                              \
    th[18]=q11*z1; th[19]=q11*z2; th[20]=q22*z1; th[21]=q22*z2;               \
    float b0 = eb0, b1 = eb1, b2 = eb2;                                       \
    _Pragma("unroll")                                                         \
    for (int k = 0; k < SD; ++k) {                                            \
      b0 += ew[0][k]*th[k]; b1 += ew[1][k]*th[k]; b2 += ew[2][k]*th[k];       \
    }                                                                         \
    if (lane < 3) {                                                           \
      const float zv = (lane==0) ? z0   : (lane==1) ? z1   : z2;              \
      const float dv = (lane==0) ? (DV0): (lane==1) ? (DV1): (DV2);           \
      const float bv = (lane==0) ? b0   : (lane==1) ? b1   : b2;              \
      out[(ROW)*3 + lane]             = zv;                                   \
      out[3*nrows + (ROW)*3 + lane]   = dv;                                   \
      out[6*nrows + (ROW)*3 + lane]   = bv;                                   \
    }                                                                         \
    float4 xbv, dxbv;                                                         \
    xbv.x  = jd0.x*z0 + jd0.y*z1 + jd0.z*z2 + jd0.w;                          \
    xbv.y  = jd1.x*z0 + jd1.y*z1 + jd1.z*z2 + jd1.w;                          \
    xbv.z  = jd2.x*z0 + jd2.y*z1 + jd2.z*z2 + jd2.w;                          \
    xbv.w  = jd3.x*z0 + jd3.y*z1 + jd3.z*z2 + jd3.w;                          \
    dxbv.x = jd0.x*b0 + jd0.y*b1 + jd0.z*b2;                                  \
    dxbv.y = jd1.x*b0 + jd1.y*b1 + jd1.z*b2;                                  \
    dxbv.z = jd2.x*b0 + jd2.y*b1 + jd2.z*b2;                                  \
    dxbv.w = jd3.x*b0 + jd3.y*b1 + jd3.z*b2;                                  \
    *(float4*)(out + xbBase  + (ROW)*D + lane*4) = xbv;                       \
    *(float4*)(out + dxbBase + (ROW)*D + lane*4) = dxbv;                      \
  }

__global__ __launch_bounds__(256) void sindy_fused(
    const float* __restrict__ x, const float* __restrict__ dx,
    const float* __restrict__ EW, const float* __restrict__ Eb,
    const float* __restrict__ ws, float* __restrict__ out, int nrows)
{
    const int lane = threadIdx.x & 31;   // lane within half-wave
    const int half = threadIdx.x >> 5;   // 0..7 within block

    // Hoisted fused weights (uniform or lane-indexed; loaded once)
    const float4 je0 = *(const float4*)(ws + 0 * D + lane * 4);
    const float4 je1 = *(const float4*)(ws + 1 * D + lane * 4);
    const float4 je2 = *(const float4*)(ws + 2 * D + lane * 4);
    const float benc0 = ws[384], benc1 = ws[385], benc2 = ws[386];
    const float4 jd0 = ((const float4*)(ws + 512))[lane * 4 + 0];
    const float4 jd1 = ((const float4*)(ws + 512))[lane * 4 + 1];
    const float4 jd2 = ((const float4*)(ws + 512))[lane * 4 + 2];
    const float4 jd3 = ((const float4*)(ws + 512))[lane * 4 + 3];

    float ew[LAT][SD];
    #pragma unroll
    for (int r = 0; r < LAT; ++r)
        #pragma unroll
        for (int k = 0; k < SD; ++k) ew[r][k] = EW[r * SD + k];
    const float eb0 = Eb[0], eb1 = Eb[1], eb2 = Eb[2];

    const int xbBase  = 9 * nrows;
    const int dxbBase = 137 * nrows;
    const int stride  = gridDim.x * 16;   // rows consumed per grid sweep

    int r = blockIdx.x * 16 + half;       // row A; row B = r + 8

    float4 cxa, cda, cxb, cdb;
    if (r < nrows) {
        cxa = *(const float4*)(x  + r * D + lane * 4);
        cda = *(const float4*)(dx + r * D + lane * 4);
    }
    if (r + 8 < nrows) {
        cxb = *(const float4*)(x  + (r + 8) * D + lane * 4);
        cdb = *(const float4*)(dx + (r + 8) * D + lane * 4);
    }

    while (r < nrows) {
        const int nr = r + stride;
        // ---- prefetch next iteration's loads (issued before compute) ----
        float4 nxa = cxa, nda = cda, nxb = cxb, ndb = cdb;
        if (nr < nrows) {
            nxa = *(const float4*)(x  + nr * D + lane * 4);
            nda = *(const float4*)(dx + nr * D + lane * 4);
        }
        if (nr + 8 < nrows) {
            nxb = *(const float4*)(x  + (nr + 8) * D + lane * 4);
            ndb = *(const float4*)(dx + (nr + 8) * D + lane * 4);
        }

        // ---- partial dots: 12 values, rows A (r) and B (r+8) ----
        float za0 = je0.x*cxa.x + je0.y*cxa.y + je0.z*cxa.z + je0.w*cxa.w;
        float za1 = je1.x*cxa.x + je1.y*cxa.y + je1.z*cxa.z + je1.w*cxa.w;
        float za2 = je2.x*cxa.x + je2.y*cxa.y + je2.z*cxa.z + je2.w*cxa.w;
        float da0 = je0.x*cda.x + je0.y*cda.y + je0.z*cda.z + je0.w*cda.w;
        float da1 = je1.x*cda.x + je1.y*cda.y + je1.z*cda.z + je1.w*cda.w;
        float da2 = je2.x*cda.x + je2.y*cda.y + je2.z*cda.z + je2.w*cda.w;
        float zb0 = je0.x*cxb.x + je0.y*cxb.y + je0.z*cxb.z + je0.w*cxb.w;
        float zb1 = je1.x*cxb.x + je1.y*cxb.y + je1.z*cxb.z + je1.w*cxb.w;
        float zb2 = je2.x*cxb.x + je2.y*cxb.y + je2.z*cxb.z + je2.w*cxb.w;
        float db0 = je0.x*cdb.x + je0.y*cdb.y + je0.z*cdb.z + je0.w*cdb.w;
        float db1 = je1.x*cdb.x + je1.y*cdb.y + je1.z*cdb.z + je1.w*cdb.w;
        float db2 = je2.x*cdb.x + je2.y*cdb.y + je2.z*cdb.z + je2.w*cdb.w;

        // ---- interleaved butterfly: 12 independent chains per step ----
        #pragma unroll
        for (int m = 16; m >= 1; m >>= 1) {
            za0 += __shfl_xor(za0, m);  za1 += __shfl_xor(za1, m);
            za2 += __shfl_xor(za2, m);  da0 += __shfl_xor(da0, m);
            da1 += __shfl_xor(da1, m);  da2 += __shfl_xor(da2, m);
            zb0 += __shfl_xor(zb0, m);  zb1 += __shfl_xor(zb1, m);
            zb2 += __shfl_xor(zb2, m);  db0 += __shfl_xor(db0, m);
            db1 += __shfl_xor(db1, m);  db2 += __shfl_xor(db2, m);
        }

        EMIT_ROW(r, za0, za1, za2, da0, da1, da2);
        if (r + 8 < nrows) {
            EMIT_ROW(r + 8, zb0, zb1, zb2, db0, db1, db2);
        }

        cxa = nxa; cda = nda; cxb = nxb; cdb = ndb;
        r = nr;
    }
}

extern "C" void kernel_launch(void* const* d_in, const int* in_sizes, int n_in,
                              void* d_out, int out_size, void* d_ws, size_t ws_size,
                              hipStream_t stream) {
    const float* x   = (const float*)d_in[0];
    const float* dx  = (const float*)d_in[1];
    const float* We1 = (const float*)d_in[2];
    const float* be1 = (const float*)d_in[3];
    const float* We2 = (const float*)d_in[4];
    const float* be2 = (const float*)d_in[5];
    const float* We3 = (const float*)d_in[6];
    const float* be3 = (const float*)d_in[7];
    const float* Wd1 = (const float*)d_in[8];
    const float* bd1 = (const float*)d_in[9];
    const float* Wd2 = (const float*)d_in[10];
    const float* bd2 = (const float*)d_in[11];
    const float* Wd3 = (const float*)d_in[12];
    const float* bd3 = (const float*)d_in[13];
    const float* EW  = (const float*)d_in[14];
    const float* Eb  = (const float*)d_in[15];

    float* ws  = (float*)d_ws;
    float* out = (float*)d_out;
    const int nrows = in_sizes[0] / D;   // 262144

    fuse_weights<<<1, 256, 0, stream>>>(We1, be1, We2, be2, We3, be3,
                                        Wd1, bd1, Wd2, bd2, Wd3, bd3, ws);

    // memory-bound: grid-stride, 16 rows per block per iteration
    sindy_fused<<<2048, 256, 0, stream>>>(x, dx, EW, Eb, ws, out, nrows);
}

// Round 3
// 123.070 us; speedup vs baseline: 1.0590x; 1.0590x over previous
//
#include <hip/hip_runtime.h>

#define D 128

typedef float f32x4 __attribute__((ext_vector_type(4)));

// ---------------------------------------------------------------------------
// Kernel 0: fold the two linear chains into fused affine maps, stored in ws:
//   ws[0..383]    : J_enc [3][128]  = We3@We2@We1
//   ws[384..386]  : b_enc [3]       = We3@(We2@be1 + be2) + be3
//   ws[512..1023] : J_dec4 [128][4] = (J_dec[c][0..2], b_dec[c])
//                   J_dec = Wd3@Wd2@Wd1, b_dec = Wd3@(Wd2@bd1 + bd2) + bd3
// One block, 256 threads. Rewrites every used slot each call (deterministic).
// ---------------------------------------------------------------------------
__global__ __launch_bounds__(256) void fuse_weights(
    const float* __restrict__ We1, const float* __restrict__ be1,
    const float* __restrict__ We2, const float* __restrict__ be2,
    const float* __restrict__ We3, const float* __restrict__ be3,
    const float* __restrict__ Wd1, const float* __restrict__ bd1,
    const float* __restrict__ Wd2, const float* __restrict__ bd2,
    const float* __restrict__ Wd3, const float* __restrict__ bd3,
    float* __restrict__ ws)
{
    __shared__ float A1[3][64];   // We3@We2
    __shared__ float B1[64][3];   // Wd2@Wd1
    __shared__ float t2d[64];     // Wd2@bd1 + bd2
    const int t = threadIdx.x;

    if (t < 192) {
        {   // A1[r][c], r<3, c<64: dot over 32
            int r = t >> 6, c = t & 63;
            float s = 0.f;
            #pragma unroll 8
            for (int i = 0; i < 32; ++i) s += We3[r * 32 + i] * We2[i * 64 + c];
            A1[r][c] = s;
        }
        {   // B1[o][l], o<64, l<3: dot over 32
            int o = t / 3, l = t - o * 3;
            float s = 0.f;
            #pragma unroll 8
            for (int i = 0; i < 32; ++i) s += Wd2[o * 32 + i] * Wd1[i * 3 + l];
            B1[o][l] = s;
        }
    } else {
        int i = t - 192;  // 0..63
        float s = bd2[i];
        #pragma unroll 8
        for (int j = 0; j < 32; ++j) s += Wd2[i * 32 + j] * bd1[j];
        t2d[i] = s;
    }
    __syncthreads();

    // J_enc [3][128]: dot over 64
    for (int e = t; e < 3 * D; e += 256) {
        int r = e >> 7, c = e & 127;
        float s = 0.f;
        #pragma unroll 8
        for (int j = 0; j < 64; ++j) s += A1[r][j] * We1[j * D + c];
        ws[e] = s;
    }
    // b_enc [3]
    if (t < 3) {
        float s = be3[t];
        #pragma unroll 8
        for (int j = 0; j < 64; ++j) s += A1[t][j] * be1[j];
        #pragma unroll 8
        for (int i = 0; i < 32; ++i) s += We3[t * 32 + i] * be2[i];
        ws[384 + t] = s;
    }
    // J_dec4 [128][4]
    if (t < 128) {
        float s0 = 0.f, s1 = 0.f, s2 = 0.f, sb = bd3[t];
        #pragma unroll 8
        for (int j = 0; j < 64; ++j) {
            float w = Wd3[t * 64 + j];
            s0 += w * B1[j][0];
            s1 += w * B1[j][1];
            s2 += w * B1[j][2];
            sb += w * t2d[j];
        }
        ws[512 + t * 4 + 0] = s0;
        ws[512 + t * 4 + 1] = s1;
        ws[512 + t * 4 + 2] = s2;
        ws[512 + t * 4 + 3] = sb;
    }
}

// ---------------------------------------------------------------------------
// Kernel 1: encoder + SINDy. Reads x, dx (nt); writes z, dz, dzb only.
// Half-wave (32 lanes) per row; block owns 128 contiguous rows (16 iters
// of 8 rows). Butterfly reduce within the half; theta+dzb per lane.
// Output layout: z @ 0 [N,3], dz @ 3N, dzb @ 6N.
// ---------------------------------------------------------------------------
__global__ __launch_bounds__(256) void enc_sindy(
    const float* __restrict__ x, const float* __restrict__ dx,
    const float* __restrict__ EW, const float* __restrict__ Eb,
    const float* __restrict__ ws, float* __restrict__ out, int nrows)
{
    const int lane = threadIdx.x & 31;
    const int half = threadIdx.x >> 5;

    const f32x4 je0 = *((const f32x4*)(ws + 0 * D) + lane);
    const f32x4 je1 = *((const f32x4*)(ws + 1 * D) + lane);
    const f32x4 je2 = *((const f32x4*)(ws + 2 * D) + lane);
    const float benc0 = ws[384], benc1 = ws[385], benc2 = ws[386];

    // EW rows; constant-term columns (th[0..2]==1) folded into the bias.
    float ew0[19], ew1[19], ew2[19];
    #pragma unroll
    for (int k = 0; k < 19; ++k) {
        ew0[k] = EW[ 3 + k];
        ew1[k] = EW[25 + k];
        ew2[k] = EW[47 + k];
    }
    const float bs0 = Eb[0] + EW[ 0] + EW[ 1] + EW[ 2];
    const float bs1 = Eb[1] + EW[22] + EW[23] + EW[24];
    const float bs2 = Eb[2] + EW[44] + EW[45] + EW[46];

    const int base = blockIdx.x * 128;

    for (int i = 0; i < 16; ++i) {
        const int row = base + i * 8 + half;
        if (row >= nrows) continue;

        const f32x4 xv  = __builtin_nontemporal_load((const f32x4*)(x  + row * D) + lane);
        const f32x4 dxv = __builtin_nontemporal_load((const f32x4*)(dx + row * D) + lane);

        float z0 = je0.x*xv.x + je0.y*xv.y + je0.z*xv.z + je0.w*xv.w;
        float z1 = je1.x*xv.x + je1.y*xv.y + je1.z*xv.z + je1.w*xv.w;
        float z2 = je2.x*xv.x + je2.y*xv.y + je2.z*xv.z + je2.w*xv.w;
        float d0 = je0.x*dxv.x + je0.y*dxv.y + je0.z*dxv.z + je0.w*dxv.w;
        float d1 = je1.x*dxv.x + je1.y*dxv.y + je1.z*dxv.z + je1.w*dxv.w;
        float d2 = je2.x*dxv.x + je2.y*dxv.y + je2.z*dxv.z + je2.w*dxv.w;

        #pragma unroll
        for (int m = 16; m >= 1; m >>= 1) {
            z0 += __shfl_xor(z0, m);  z1 += __shfl_xor(z1, m);
            z2 += __shfl_xor(z2, m);  d0 += __shfl_xor(d0, m);
            d1 += __shfl_xor(d1, m);  d2 += __shfl_xor(d2, m);
        }

        z0 += benc0; z1 += benc1; z2 += benc2;

        const float q00 = z0*z0, q01 = z0*z1, q02 = z0*z2;
        const float q11 = z1*z1, q12 = z1*z2, q22 = z2*z2;
        const float c0 = q00*z0, c1 = q00*z1, c2 = q00*z2;
        const float c3 = q11*z0, c4 = q12*z0, c5 = q22*z0;
        const float c6 = q11*z1, c7 = q11*z2, c8 = q22*z1, c9 = q22*z2;

        float b0 = bs0, b1 = bs1, b2 = bs2;
        #define ACC(K, V) { b0 += ew0[K]*(V); b1 += ew1[K]*(V); b2 += ew2[K]*(V); }
        ACC(0, z0)  ACC(1, z1)  ACC(2, z2)
        ACC(3, q00) ACC(4, q01) ACC(5, q02) ACC(6, q11) ACC(7, q12) ACC(8, q22)
        ACC(9, c0)  ACC(10, c1) ACC(11, c2) ACC(12, c3) ACC(13, c4)
        ACC(14, c5) ACC(15, c6) ACC(16, c7) ACC(17, c8) ACC(18, c9)
        #undef ACC

        if (lane < 3) {
            const float zv = (lane == 0) ? z0 : (lane == 1) ? z1 : z2;
            const float dv = (lane == 0) ? d0 : (lane == 1) ? d1 : d2;
            const float bv = (lane == 0) ? b0 : (lane == 1) ? b1 : b2;
            out[row * 3 + lane]             = zv;
            out[3 * nrows + row * 3 + lane] = dv;
            out[6 * nrows + row * 3 + lane] = bv;
        }
    }
}

// ---------------------------------------------------------------------------
// Kernel 2: decoder. Reads z, dzb (tiny, L2/L3-hot); writes xb, dxb (nt).
// Half-wave per row; block owns 128 contiguous rows. ~40 VGPRs, pure
// store-streamer.
// ---------------------------------------------------------------------------
__global__ __launch_bounds__(256) void dec_kernel(
    const float* __restrict__ ws, const float* __restrict__ zin,
    const float* __restrict__ dzbin, float* __restrict__ xbout,
    float* __restrict__ dxbout, int nrows)
{
    const int lane = threadIdx.x & 31;
    const int half = threadIdx.x >> 5;

    const f32x4 jd0 = *((const f32x4*)(ws + 512) + lane * 4 + 0);
    const f32x4 jd1 = *((const f32x4*)(ws + 512) + lane * 4 + 1);
    const f32x4 jd2 = *((const f32x4*)(ws + 512) + lane * 4 + 2);
    const f32x4 jd3 = *((const f32x4*)(ws + 512) + lane * 4 + 3);

    const int base = blockIdx.x * 128;

    #pragma unroll 4
    for (int i = 0; i < 16; ++i) {
        const int row = base + i * 8 + half;
        if (row >= nrows) continue;

        const float z0 = zin[row * 3 + 0];
        const float z1 = zin[row * 3 + 1];
        const float z2 = zin[row * 3 + 2];
        const float b0 = dzbin[row * 3 + 0];
        const float b1 = dzbin[row * 3 + 1];
        const float b2 = dzbin[row * 3 + 2];

        f32x4 xbv, dxbv;
        xbv.x  = jd0.x*z0 + jd0.y*z1 + jd0.z*z2 + jd0.w;
        xbv.y  = jd1.x*z0 + jd1.y*z1 + jd1.z*z2 + jd1.w;
        xbv.z  = jd2.x*z0 + jd2.y*z1 + jd2.z*z2 + jd2.w;
        xbv.w  = jd3.x*z0 + jd3.y*z1 + jd3.z*z2 + jd3.w;
        dxbv.x = jd0.x*b0 + jd0.y*b1 + jd0.z*b2;
        dxbv.y = jd1.x*b0 + jd1.y*b1 + jd1.z*b2;
        dxbv.z = jd2.x*b0 + jd2.y*b1 + jd2.z*b2;
        dxbv.w = jd3.x*b0 + jd3.y*b1 + jd3.z*b2;

        __builtin_nontemporal_store(xbv,  (f32x4*)(xbout  + row * D) + lane);
        __builtin_nontemporal_store(dxbv, (f32x4*)(dxbout + row * D) + lane);
    }
}

extern "C" void kernel_launch(void* const* d_in, const int* in_sizes, int n_in,
                              void* d_out, int out_size, void* d_ws, size_t ws_size,
                              hipStream_t stream) {
    const float* x   = (const float*)d_in[0];
    const float* dx  = (const float*)d_in[1];
    const float* We1 = (const float*)d_in[2];
    const float* be1 = (const float*)d_in[3];
    const float* We2 = (const float*)d_in[4];
    const float* be2 = (const float*)d_in[5];
    const float* We3 = (const float*)d_in[6];
    const float* be3 = (const float*)d_in[7];
    const float* Wd1 = (const float*)d_in[8];
    const float* bd1 = (const float*)d_in[9];
    const float* Wd2 = (const float*)d_in[10];
    const float* bd2 = (const float*)d_in[11];
    const float* Wd3 = (const float*)d_in[12];
    const float* bd3 = (const float*)d_in[13];
    const float* EW  = (const float*)d_in[14];
    const float* Eb  = (const float*)d_in[15];

    float* ws  = (float*)d_ws;
    float* out = (float*)d_out;
    const int nrows = in_sizes[0] / D;        // 262144
    const int nblk  = (nrows + 127) / 128;    // 2048

    fuse_weights<<<1, 256, 0, stream>>>(We1, be1, We2, be2, We3, be3,
                                        Wd1, bd1, Wd2, bd2, Wd3, bd3, ws);

    enc_sindy<<<nblk, 256, 0, stream>>>(x, dx, EW, Eb, ws, out, nrows);

    dec_kernel<<<nblk, 256, 0, stream>>>(ws,
                                         out,              // z
                                         out + 6 * (size_t)nrows,   // dzb
                                         out + 9 * (size_t)nrows,   // xb
                                         out + 137 * (size_t)nrows, // dxb
                                         nrows);
}